// Round 7
// baseline (152.413 us; speedup 1.0000x reference)
//
#include <hip/hip_runtime.h>
#include <hip/hip_bf16.h>
#include <cmath>

#define Bsz 8
#define Csz 512
#define Lsz 4096
#define LPOOL 511
#define NEGV -1000000000.0f

typedef __attribute__((ext_vector_type(8))) short short8;
typedef __attribute__((ext_vector_type(4))) float float4v;

__device__ __forceinline__ float bf2f(short u) {
  unsigned int x = ((unsigned int)(unsigned short)u) << 16;
  return __builtin_bit_cast(float, x);
}

// fast tanh: 1 - 2/(e^{2x}+1); rel err ~1e-5, far below bf16 gemm noise
__device__ __forceinline__ float ftanh(float x) {
  float e = __expf(2.0f * x);
  return 1.0f - 2.0f * __builtin_amdgcn_rcpf(e + 1.0f);
}

// ---------------------------------------------------------------------------
// prep: block 0 = mask-width detect; blocks 1..128 = W f32 -> Wts bf16 tiled.
__global__ __launch_bounds__(256) void prep(const unsigned char* __restrict__ mb,
    int* __restrict__ flag, const float* __restrict__ W,
    __hip_bfloat16* __restrict__ Wts) {
  const int tid = threadIdx.x;
  const int pb = blockIdx.x;
  if (pb == 0) {
    __shared__ int sf;
    if (tid == 0) sf = 0;
    __syncthreads();
    int f = 0;
    for (int i = tid; i < 4096; i += 256)
      if ((i & 3) && mb[i]) f = 1;
    if (f) atomicOr(&sf, 1);
    __syncthreads();
    if (tid == 0) *flag = sf;  // 0 = int32 mask, 1 = uint8 mask
  } else {
    int tg = (pb - 1) * 256 + tid;
    int d = tg >> 6, cg = tg & 63;
    float4 w0 = *(const float4*)(W + (size_t)d * 512 + cg * 8);
    float4 w1 = *(const float4*)(W + (size_t)d * 512 + cg * 8 + 4);
    __hip_bfloat16 hb[8];
    hb[0] = __float2bfloat16(w0.x); hb[1] = __float2bfloat16(w0.y);
    hb[2] = __float2bfloat16(w0.z); hb[3] = __float2bfloat16(w0.w);
    hb[4] = __float2bfloat16(w1.x); hb[5] = __float2bfloat16(w1.y);
    hb[6] = __float2bfloat16(w1.z); hb[7] = __float2bfloat16(w1.w);
    int nt = d >> 7, row = d & 127, ks = cg >> 2, seg = cg & 3;
    *(short8*)(Wts + (((size_t)nt * 16 + ks) * 512 + seg * 128 + row) * 8) = *(short8*)hb;
  }
}

// ---------------------------------------------------------------------------
// gemm_fused v7: 1024 blocks x 128 thr (2 waves), 32 m-rows each, ~37.3 KiB
// LDS -> 4 independent blocks/CU (8 waves/CU with max inter-block overlap).
// Phase 1: per-wave transpose (wave owns 16 l-cols, depth-3 global prefetch,
// pitch-21 LDS stage, 2-way-max banks, compiler-counted lgkm only).
// Phase 2: barrier-free k-loop: A-frags from read-only sA; B-frags from
// L2-resident Wts straight to a register ping-pong, one k-step ahead.
// Per-nt tanh epilogue in registers; single cross-wave reduce at the end.
__global__ __launch_bounds__(128, 2) void gemm_fused(
    const float* __restrict__ x, const __hip_bfloat16* __restrict__ Wts,
    const float* __restrict__ bias, const float* __restrict__ v,
    float* __restrict__ s) {
  __shared__ short8 sA[2048];                    // 32 KiB: A 32m x 512k tiled
  __shared__ float sXw2[2][672];                 // 5.25 KiB: per-wave [32][21]

  const int tid = threadIdx.x;
  const int lane = tid & 63, wave = tid >> 6;    // wave in {0,1}
  const int mt = blockIdx.x;                     // 0..1023
  const int b = mt >> 7;
  const int l0 = (mt & 127) << 5;                // 32 l-rows per block

  // ---------------- phase 1: per-wave transpose, no block barriers ----------
  {
    float* sXw = sXw2[wave];
    const int r = lane >> 1;                     // c-row within 32-c chunk
    const int q = lane & 1;                      // 8-float half of wave's 16 l
    const int ll = lane & 15, ks2 = lane >> 4;   // read-side task
    const float* xg = x + (((size_t)(b * Csz + r)) << 12) + (size_t)(l0 + wave * 16 + q * 8);

    float4 A0a = *(const float4*)(xg);
    float4 A0b = *(const float4*)(xg + 4);
    float4 A1a = *(const float4*)(xg + (1u << 17));
    float4 A1b = *(const float4*)(xg + (1u << 17) + 4);
    float4 A2a = *(const float4*)(xg + (2u << 17));
    float4 A2b = *(const float4*)(xg + (2u << 17) + 4);

    #pragma unroll
    for (int cc = 0; cc < 16; ++cc) {
      float4 Na = A2a, Nb = A2b;
      if (cc < 13) {
        const float* xn = xg + ((size_t)(cc + 3) << 17);
        Na = *(const float4*)(xn);
        Nb = *(const float4*)(xn + 4);
      }
      // stage 8 floats elementwise (pitch 21: 2-way max bank aliasing)
      float* wp = &sXw[r * 21 + q * 8];
      wp[0] = A0a.x; wp[1] = A0a.y; wp[2] = A0a.z; wp[3] = A0a.w;
      wp[4] = A0b.x; wp[5] = A0b.y; wp[6] = A0b.z; wp[7] = A0b.w;
      // transposed read: 8 consecutive c's for one l (2-way banks, free)
      float tv[8];
      #pragma unroll
      for (int j = 0; j < 8; ++j) tv[j] = sXw[(ks2 * 8 + j) * 21 + ll];
      __hip_bfloat16 ab[8];
      #pragma unroll
      for (int j = 0; j < 8; ++j) ab[j] = __float2bfloat16(tv[j]);
      sA[(cc * 4 + ks2) * 32 + wave * 16 + ll] = *(short8*)ab;
      A0a = A1a; A0b = A1b; A1a = A2a; A1b = A2b; A2a = Na; A2b = Nb;
    }
  }

  const int lr = lane & 15, quad = lane >> 4;
  const int nh = wave;                           // wave picks the n-half

  __syncthreads();   // sA complete; phase 2 is read-only on LDS

  // ---------------- phase 2: barrier-free nt/k loop -------------------------
  const short8* Bp = (const short8*)Wts + quad * 128 + nh * 64 + lr;
#define LDB(dst, idx)                                                          \
  {                                                                            \
    const short8* bp = Bp + ((size_t)(idx) << 9);                              \
    dst[0] = bp[0]; dst[1] = bp[16]; dst[2] = bp[32]; dst[3] = bp[48];         \
  }
  short8 bA[4], bB[4];
  LDB(bA, 0)

  float sp[2][4];
  #pragma unroll
  for (int mf = 0; mf < 2; ++mf)
    #pragma unroll
    for (int reg = 0; reg < 4; ++reg) sp[mf][reg] = 0.f;

  #pragma unroll
  for (int nt = 0; nt < 4; ++nt) {
    // bias/v fragments for this nt (L1-hot; reloading saves VGPR)
    float bl[4], vl[4];
    #pragma unroll
    for (int nf = 0; nf < 4; ++nf) {
      int n = nt * 128 + nh * 64 + nf * 16 + lr;
      bl[nf] = bias[n];
      vl[nf] = v[n];
    }
    float4v acc[2][4];
    #pragma unroll
    for (int mf = 0; mf < 2; ++mf)
      #pragma unroll
      for (int nf = 0; nf < 4; ++nf) acc[mf][nf] = (float4v)0.f;

    #pragma unroll
    for (int k2 = 0; k2 < 8; ++k2) {
      const int ks = k2 * 2;
      const int idx = nt * 16 + ks;
      if (idx + 1 < 64) LDB(bB, idx + 1)
      {
        short8 af[2];
        #pragma unroll
        for (int mf = 0; mf < 2; ++mf)
          af[mf] = sA[(ks * 4 + quad) * 32 + mf * 16 + lr];
        __builtin_amdgcn_s_setprio(1);
        #pragma unroll
        for (int mf = 0; mf < 2; ++mf)
          #pragma unroll
          for (int nf = 0; nf < 4; ++nf)
            acc[mf][nf] = __builtin_amdgcn_mfma_f32_16x16x32_bf16(
                af[mf], bA[nf], acc[mf][nf], 0, 0, 0);
        __builtin_amdgcn_s_setprio(0);
      }
      if (idx + 2 < 64) LDB(bA, idx + 2)
      {
        short8 af[2];
        #pragma unroll
        for (int mf = 0; mf < 2; ++mf)
          af[mf] = sA[((ks + 1) * 4 + quad) * 32 + mf * 16 + lr];
        __builtin_amdgcn_s_setprio(1);
        #pragma unroll
        for (int mf = 0; mf < 2; ++mf)
          #pragma unroll
          for (int nf = 0; nf < 4; ++nf)
            acc[mf][nf] = __builtin_amdgcn_mfma_f32_16x16x32_bf16(
                af[mf], bB[nf], acc[mf][nf], 0, 0, 0);
        __builtin_amdgcn_s_setprio(0);
      }
    }
    // epilogue for this nt (pure registers)
    #pragma unroll
    for (int mf = 0; mf < 2; ++mf)
      #pragma unroll
      for (int reg = 0; reg < 4; ++reg) {
        float pp = 0.f;
        #pragma unroll
        for (int nf = 0; nf < 4; ++nf)
          pp += ftanh(acc[mf][nf][reg] + bl[nf]) * vl[nf];
        sp[mf][reg] += pp;
      }
  }
#undef LDB

  // reduce over the 16 n-lanes; combine the two nh waves via staging space
  float* sRed = (float*)sXw2;              // 32 floats needed; sXw dead
  float pv[2][4];
  #pragma unroll
  for (int mf = 0; mf < 2; ++mf)
    #pragma unroll
    for (int reg = 0; reg < 4; ++reg) {
      float p = sp[mf][reg];
      p += __shfl_xor(p, 1, 16);
      p += __shfl_xor(p, 2, 16);
      p += __shfl_xor(p, 4, 16);
      p += __shfl_xor(p, 8, 16);
      pv[mf][reg] = p;
    }
  __syncthreads();                         // re-sync drifted waves before sRed
  if (nh == 1 && lr == 0) {
    #pragma unroll
    for (int mf = 0; mf < 2; ++mf)
      #pragma unroll
      for (int reg = 0; reg < 4; ++reg)
        sRed[mf * 16 + quad * 4 + reg] = pv[mf][reg];
  }
  __syncthreads();
  if (nh == 0 && lr == 0) {
    #pragma unroll
    for (int mf = 0; mf < 2; ++mf)
      #pragma unroll
      for (int reg = 0; reg < 4; ++reg)
        s[mt * 32 + mf * 16 + quad * 4 + reg] =
            pv[mf][reg] + sRed[mf * 16 + quad * 4 + reg];
  }
}

// ---------------------------------------------------------------------------
// pool2 v7: per-thread sliding window. Block = (8-window group, b, c-half);
// thread owns one c-row: loads 72 contiguous floats once (every byte used),
// computes 8 window dots against LDS weights (float4 broadcast reads).
__global__ __launch_bounds__(256) void pool2(const float* __restrict__ x,
    const float* __restrict__ s, const void* __restrict__ mask,
    const int* __restrict__ flag, float* __restrict__ out) {
  __shared__ __align__(16) float wl[8][16];
  const int t = threadIdx.x;
  const int bx = blockIdx.x;
  const int p0 = bx * 8, b = blockIdx.y, ch = blockIdx.z;
  if (t < 8 && p0 + t < LPOOL) {
    const int p = p0 + t;
    const bool u8 = (*flag != 0);
    const unsigned char* m8 = (const unsigned char*)mask;
    const int* m32 = (const int*)mask;
    const int base = b * Lsz + p * 8;
    float sv[16]; int mv[16];
    float mx = -3.4e38f;
    #pragma unroll
    for (int w = 0; w < 16; ++w) {
      int mk = u8 ? (int)m8[base + w] : m32[base + w];
      float val = mk ? NEGV : s[base + w];
      sv[w] = val; mv[w] = mk;
      mx = fmaxf(mx, val);
    }
    float sum = 0.f;
    #pragma unroll
    for (int w = 0; w < 16; ++w) { sv[w] = expf(sv[w] - mx); sum += sv[w]; }
    float inv = 1.0f / sum;
    float norm = 0.f;
    #pragma unroll
    for (int w = 0; w < 16; ++w) { sv[w] = mv[w] ? 0.f : sv[w] * inv; norm += sv[w]; }
    norm = fmaxf(norm, 1e-6f);
    float rn = 1.0f / norm;
    #pragma unroll
    for (int w = 0; w < 16; ++w) wl[t][w] = sv[w] * rn;
  }
  __syncthreads();
  const int c = ch * 256 + t;
  const float* xp = x + ((size_t)b * Csz + c) * Lsz + p0 * 8;
  float fb[72];
  #pragma unroll
  for (int i = 0; i < 16; ++i) {
    float4 vv = *(const float4*)(xp + i * 4);
    fb[i * 4 + 0] = vv.x; fb[i * 4 + 1] = vv.y;
    fb[i * 4 + 2] = vv.z; fb[i * 4 + 3] = vv.w;
  }
  const bool full = (bx < 63);                 // last group has 7 windows
  if (full) {
    float4 v16 = *(const float4*)(xp + 64);
    float4 v17 = *(const float4*)(xp + 68);
    fb[64] = v16.x; fb[65] = v16.y; fb[66] = v16.z; fb[67] = v16.w;
    fb[68] = v17.x; fb[69] = v17.y; fb[70] = v17.z; fb[71] = v17.w;
  } else {
    #pragma unroll
    for (int i = 64; i < 72; ++i) fb[i] = 0.f;
  }
  float* ob = out + ((size_t)b * Csz + c) * LPOOL + p0;
  #pragma unroll
  for (int j = 0; j < 8; ++j) {
    if (j == 7 && !full) break;
    float4 w0 = *(const float4*)(&wl[j][0]);
    float4 w1 = *(const float4*)(&wl[j][4]);
    float4 w2 = *(const float4*)(&wl[j][8]);
    float4 w3 = *(const float4*)(&wl[j][12]);
    float acc = fb[8*j+0] * w0.x + fb[8*j+1] * w0.y + fb[8*j+2] * w0.z + fb[8*j+3] * w0.w
              + fb[8*j+4] * w1.x + fb[8*j+5] * w1.y + fb[8*j+6] * w1.z + fb[8*j+7] * w1.w
              + fb[8*j+8] * w2.x + fb[8*j+9] * w2.y + fb[8*j+10] * w2.z + fb[8*j+11] * w2.w
              + fb[8*j+12] * w3.x + fb[8*j+13] * w3.y + fb[8*j+14] * w3.z + fb[8*j+15] * w3.w;
    ob[j] = acc;
  }
}

// ---------------------------------------------------------------------------
// Fallback path kernels (only if ws too small for bf16 path)
__global__ void detect_mask(const unsigned char* __restrict__ mb, int* __restrict__ flag) {
  __shared__ int sf;
  int t = threadIdx.x;
  if (t == 0) sf = 0;
  __syncthreads();
  int f = 0;
  for (int i = t; i < 4096; i += 256)
    if ((i & 3) && mb[i]) f = 1;
  if (f) atomicOr(&sf, 1);
  __syncthreads();
  if (t == 0) *flag = sf;
}

__global__ __launch_bounds__(256) void gemm_s_f32(const float* __restrict__ x,
    const float* __restrict__ W, const float* __restrict__ bias,
    const float* __restrict__ v, float* __restrict__ s_out) {
  __shared__ float sA[32][64];
  __shared__ float sB[32][68];
  __shared__ float s_acc[64];
  const int tid = threadIdx.x;
  const int b = blockIdx.y;
  const int l0 = blockIdx.x * 64;
  if (tid < 64) s_acc[tid] = 0.0f;
  const int tx = tid & 15;
  const int ty = tid >> 4;
  const float* xb = x + ((size_t)b * Csz) * Lsz + l0;
  for (int d0 = 0; d0 < Csz; d0 += 64) {
    float acc[4][4] = {{0.f}};
    for (int c0 = 0; c0 < Csz; c0 += 32) {
      __syncthreads();
      #pragma unroll
      for (int it = 0; it < 8; ++it) {
        int idx = tid + it * 256;
        int kc = idx >> 6, ml = idx & 63;
        sA[kc][ml] = xb[(size_t)(c0 + kc) * Lsz + ml];
      }
      #pragma unroll
      for (int it = 0; it < 8; ++it) {
        int idx = tid + it * 256;
        int kc = idx & 31, dj = idx >> 5;
        sB[kc][dj] = W[(size_t)(d0 + dj) * Csz + c0 + kc];
      }
      __syncthreads();
      #pragma unroll
      for (int kc = 0; kc < 32; ++kc) {
        float4 a  = *(const float4*)(&sA[kc][tx << 2]);
        float4 w4 = *(const float4*)(&sB[kc][ty << 2]);
        acc[0][0] += a.x * w4.x; acc[0][1] += a.x * w4.y; acc[0][2] += a.x * w4.z; acc[0][3] += a.x * w4.w;
        acc[1][0] += a.y * w4.x; acc[1][1] += a.y * w4.y; acc[1][2] += a.y * w4.z; acc[1][3] += a.y * w4.w;
        acc[2][0] += a.z * w4.x; acc[2][1] += a.z * w4.y; acc[2][2] += a.z * w4.z; acc[2][3] += a.z * w4.w;
        acc[3][0] += a.w * w4.x; acc[3][1] += a.w * w4.y; acc[3][2] += a.w * w4.z; acc[3][3] += a.w * w4.w;
      }
    }
    float part[4] = {0.f, 0.f, 0.f, 0.f};
    #pragma unroll
    for (int j = 0; j < 4; ++j) {
      int d = d0 + (ty << 2) + j;
      float bj = bias[d], vj = v[d];
      #pragma unroll
      for (int i = 0; i < 4; ++i)
        part[i] += tanhf(acc[i][j] + bj) * vj;
    }
    #pragma unroll
    for (int i = 0; i < 4; ++i)
      atomicAdd(&s_acc[(tx << 2) + i], part[i]);
  }
  __syncthreads();
  if (tid < 64) s_out[(size_t)b * Lsz + l0 + tid] = s_acc[tid];
}

__global__ void win_weights(const float* __restrict__ s, const void* __restrict__ mask,
                            const int* __restrict__ flag, float* __restrict__ wgt) {
  int t = blockIdx.x * blockDim.x + threadIdx.x;
  if (t >= Bsz * LPOOL) return;
  int b = t / LPOOL, p = t - b * LPOOL;
  const bool u8 = (*flag != 0);
  const unsigned char* m8 = (const unsigned char*)mask;
  const int* m32 = (const int*)mask;
  float sv[16]; int mv[16];
  float mx = -3.4e38f;
  int base = b * Lsz + p * 8;
  #pragma unroll
  for (int w = 0; w < 16; ++w) {
    int mk = u8 ? (int)m8[base + w] : m32[base + w];
    float val = mk ? NEGV : s[base + w];
    sv[w] = val; mv[w] = mk;
    mx = fmaxf(mx, val);
  }
  float sum = 0.f;
  #pragma unroll
  for (int w = 0; w < 16; ++w) { sv[w] = expf(sv[w] - mx); sum += sv[w]; }
  float inv = 1.0f / sum;
  float norm = 0.f;
  #pragma unroll
  for (int w = 0; w < 16; ++w) { sv[w] = mv[w] ? 0.f : sv[w] * inv; norm += sv[w]; }
  norm = fmaxf(norm, 1e-6f);
  float rn = 1.0f / norm;
  #pragma unroll
  for (int w = 0; w < 16; ++w) wgt[t * 16 + w] = sv[w] * rn;
}

__global__ __launch_bounds__(256) void pool_out(const float* __restrict__ x,
    const float* __restrict__ wgt, float* __restrict__ out) {
  __shared__ float xrow[Lsz];
  int bc = blockIdx.x;
  int c = bc & (Csz - 1);
  int b = bc >> 9;
  const float* xr = x + ((size_t)b * Csz + c) * Lsz;
  int tid = threadIdx.x;
  #pragma unroll
  for (int it = 0; it < 4; ++it) {
    int idx = (tid + it * 256) << 2;
    *(float4*)(&xrow[idx]) = *(const float4*)(&xr[idx]);
  }
  __syncthreads();
  const float* wb = wgt + (size_t)b * LPOOL * 16;
  float* ob = out + ((size_t)b * Csz + c) * LPOOL;
  for (int p = tid; p < LPOOL; p += 256) {
    const float4* wp = (const float4*)(wb + p * 16);
    const float4* xp = (const float4*)(&xrow[p * 8]);
    float acc = 0.f;
    #pragma unroll
    for (int q = 0; q < 4; ++q) {
      float4 wv = wp[q], xv = xp[q];
      acc += xv.x * wv.x + xv.y * wv.y + xv.z * wv.z + xv.w * wv.w;
    }
    ob[p] = acc;
  }
}

// ---------------------------------------------------------------------------
extern "C" void kernel_launch(void* const* d_in, const int* in_sizes, int n_in,
                              void* d_out, int out_size, void* d_ws, size_t ws_size,
                              hipStream_t stream) {
  const float* x    = (const float*)d_in[0];
  const void*  mask = d_in[1];
  const float* W    = (const float*)d_in[2];
  const float* bias = (const float*)d_in[3];
  const float* v    = (const float*)d_in[4];
  float* out = (float*)d_out;

  char* wsb = (char*)d_ws;
  int*   flag = (int*)wsb;                                   // 256 B
  float* s    = (float*)(wsb + 256);                         // 131072 B
  float* wgt  = (float*)(wsb + 131328);                      // 261632 B (fallback only)
  __hip_bfloat16* Wts = (__hip_bfloat16*)(wsb + 393216);     // 524288 B
  const size_t NEED = 917504;

  if (ws_size >= NEED) {
    prep<<<129, 256, 0, stream>>>((const unsigned char*)mask, flag, W, Wts);
    gemm_fused<<<1024, 128, 0, stream>>>(x, Wts, bias, v, s);
    pool2<<<dim3(64, Bsz, 2), 256, 0, stream>>>(x, s, mask, flag, out);
  } else {
    detect_mask<<<1, 256, 0, stream>>>((const unsigned char*)mask, flag);
    gemm_s_f32<<<dim3(Lsz / 64, Bsz), 256, 0, stream>>>(x, W, bias, v, s);
    win_weights<<<(Bsz * LPOOL + 255) / 256, 256, 0, stream>>>(s, mask, flag, wgt);
    pool_out<<<Bsz * Csz, 256, 0, stream>>>(x, wgt, out);
  }
}

// Round 8
// 147.047 us; speedup vs baseline: 1.0365x; 1.0365x over previous
//
#include <hip/hip_runtime.h>
#include <hip/hip_bf16.h>
#include <cmath>

#define Bsz 8
#define Csz 512
#define Lsz 4096
#define LPOOL 511
#define NEGV -1000000000.0f

typedef __attribute__((ext_vector_type(8))) short short8;
typedef __attribute__((ext_vector_type(4))) float float4v;

__device__ __forceinline__ float bf2f(short u) {
  unsigned int x = ((unsigned int)(unsigned short)u) << 16;
  return __builtin_bit_cast(float, x);
}

// fast tanh: 1 - 2/(e^{2x}+1); rel err ~1e-5, far below bf16 gemm noise
__device__ __forceinline__ float ftanh(float x) {
  float e = __expf(2.0f * x);
  return 1.0f - 2.0f * __builtin_amdgcn_rcpf(e + 1.0f);
}

// ---------------------------------------------------------------------------
// prep: block 0 = mask-width detect; blocks 1..128 = W f32 -> Wts bf16 tiled.
__global__ __launch_bounds__(256) void prep(const unsigned char* __restrict__ mb,
    int* __restrict__ flag, const float* __restrict__ W,
    __hip_bfloat16* __restrict__ Wts) {
  const int tid = threadIdx.x;
  const int pb = blockIdx.x;
  if (pb == 0) {
    __shared__ int sf;
    if (tid == 0) sf = 0;
    __syncthreads();
    int f = 0;
    for (int i = tid; i < 4096; i += 256)
      if ((i & 3) && mb[i]) f = 1;
    if (f) atomicOr(&sf, 1);
    __syncthreads();
    if (tid == 0) *flag = sf;  // 0 = int32 mask, 1 = uint8 mask
  } else {
    int tg = (pb - 1) * 256 + tid;
    int d = tg >> 6, cg = tg & 63;
    float4 w0 = *(const float4*)(W + (size_t)d * 512 + cg * 8);
    float4 w1 = *(const float4*)(W + (size_t)d * 512 + cg * 8 + 4);
    __hip_bfloat16 hb[8];
    hb[0] = __float2bfloat16(w0.x); hb[1] = __float2bfloat16(w0.y);
    hb[2] = __float2bfloat16(w0.z); hb[3] = __float2bfloat16(w0.w);
    hb[4] = __float2bfloat16(w1.x); hb[5] = __float2bfloat16(w1.y);
    hb[6] = __float2bfloat16(w1.z); hb[7] = __float2bfloat16(w1.w);
    int nt = d >> 7, row = d & 127, ks = cg >> 2, seg = cg & 3;
    *(short8*)(Wts + (((size_t)nt * 16 + ks) * 512 + seg * 128 + row) * 8) = *(short8*)hb;
  }
}

// ---------------------------------------------------------------------------
// gemm_fused v8: 512 blocks x 256 thr (4 waves), 64 m-rows each, ~69 KiB LDS
// -> 2 blocks/CU. NO barriers in any hot loop.
// Phase 1: per-wave transpose (wave owns 16 l-cols, depth-3 global prefetch,
// pitch-21 LDS stage, 2-way-max banks, compiler-counted lgkm only).
// Phase 2: barrier-free k-loop with DEPTH-4 B register pipeline (bq[idx&3],
// statically indexed under full unroll): 16 outstanding L2 loads per wave,
// issue-to-use distance ~4 k-steps -> covers ~200cy L2 latency (R7's depth-1
// exposed it). A-frags from read-only sA. Per-nt tanh epilogue in registers.
__global__ __launch_bounds__(256, 2) void gemm_fused(
    const float* __restrict__ x, const __hip_bfloat16* __restrict__ Wts,
    const float* __restrict__ bias, const float* __restrict__ v,
    float* __restrict__ s) {
  __shared__ short8 sA[4096];                    // 64 KiB: A 64m x 512k tiled
  __shared__ float sXw4[4][672];                 // 10.5 KiB: per-wave [32][21]

  const int tid = threadIdx.x;
  const int lane = tid & 63, wave = tid >> 6;
  const int mt = blockIdx.x;                     // 0..511
  const int b = mt >> 6;
  const int l0 = (mt & 63) << 6;                 // 64 l-rows per block

  // ---------------- phase 1: per-wave transpose, no block barriers ----------
  {
    float* sXw = sXw4[wave];
    const int r = lane >> 1;                     // c-row within 32-c chunk
    const int q = lane & 1;                      // 8-float half of wave's 16 l
    const int ll = lane & 15, ks2 = lane >> 4;   // read-side task
    const float* xg = x + (((size_t)(b * Csz + r)) << 12) + (size_t)(l0 + wave * 16 + q * 8);

    float4 A0a = *(const float4*)(xg);
    float4 A0b = *(const float4*)(xg + 4);
    float4 A1a = *(const float4*)(xg + (1u << 17));
    float4 A1b = *(const float4*)(xg + (1u << 17) + 4);
    float4 A2a = *(const float4*)(xg + (2u << 17));
    float4 A2b = *(const float4*)(xg + (2u << 17) + 4);

    #pragma unroll
    for (int cc = 0; cc < 16; ++cc) {
      float4 Na = A2a, Nb = A2b;
      if (cc < 13) {
        const float* xn = xg + ((size_t)(cc + 3) << 17);
        Na = *(const float4*)(xn);
        Nb = *(const float4*)(xn + 4);
      }
      // stage 8 floats elementwise (pitch 21: 2-way max bank aliasing)
      float* wp = &sXw[r * 21 + q * 8];
      wp[0] = A0a.x; wp[1] = A0a.y; wp[2] = A0a.z; wp[3] = A0a.w;
      wp[4] = A0b.x; wp[5] = A0b.y; wp[6] = A0b.z; wp[7] = A0b.w;
      // transposed read: 8 consecutive c's for one l (2-way banks, free)
      float tv[8];
      #pragma unroll
      for (int j = 0; j < 8; ++j) tv[j] = sXw[(ks2 * 8 + j) * 21 + ll];
      __hip_bfloat16 ab[8];
      #pragma unroll
      for (int j = 0; j < 8; ++j) ab[j] = __float2bfloat16(tv[j]);
      sA[(cc * 4 + ks2) * 64 + wave * 16 + ll] = *(short8*)ab;
      A0a = A1a; A0b = A1b; A1a = A2a; A1b = A2b; A2a = Na; A2b = Nb;
    }
  }

  const int lr = lane & 15, quad = lane >> 4;
  const int mh = wave >> 1, nh = wave & 1;

  __syncthreads();   // sA complete; phase 2 is read-only on LDS

  // ---------------- phase 2: barrier-free nt/k loop, depth-4 B pipeline -----
  const short8* Bp = (const short8*)Wts + quad * 128 + nh * 64 + lr;
#define LDB(dst, idx)                                                          \
  {                                                                            \
    const short8* bp = Bp + ((size_t)(idx) << 9);                              \
    dst[0] = bp[0]; dst[1] = bp[16]; dst[2] = bp[32]; dst[3] = bp[48];         \
  }
  short8 bq[4][4];                               // depth-4 pipeline, static idx
  LDB(bq[0], 0) LDB(bq[1], 1) LDB(bq[2], 2) LDB(bq[3], 3)

  float sp[2][4];
  #pragma unroll
  for (int mf = 0; mf < 2; ++mf)
    #pragma unroll
    for (int reg = 0; reg < 4; ++reg) sp[mf][reg] = 0.f;

  #pragma unroll
  for (int nt = 0; nt < 4; ++nt) {
    // bias/v fragments for this nt (L1-hot; reloading saves VGPR)
    float bl[4], vl[4];
    #pragma unroll
    for (int nf = 0; nf < 4; ++nf) {
      int n = nt * 128 + nh * 64 + nf * 16 + lr;
      bl[nf] = bias[n];
      vl[nf] = v[n];
    }
    float4v acc[2][4];
    #pragma unroll
    for (int mf = 0; mf < 2; ++mf)
      #pragma unroll
      for (int nf = 0; nf < 4; ++nf) acc[mf][nf] = (float4v)0.f;

    #pragma unroll
    for (int ks = 0; ks < 16; ++ks) {
      const int idx = nt * 16 + ks;              // compile-time after unroll
      short8 af[2];
      af[0] = sA[(ks * 4 + quad) * 64 + mh * 32 + lr];
      af[1] = sA[(ks * 4 + quad) * 64 + mh * 32 + 16 + lr];
      __builtin_amdgcn_s_setprio(1);
      #pragma unroll
      for (int mf = 0; mf < 2; ++mf)
        #pragma unroll
        for (int nf = 0; nf < 4; ++nf)
          acc[mf][nf] = __builtin_amdgcn_mfma_f32_16x16x32_bf16(
              af[mf], bq[idx & 3][nf], acc[mf][nf], 0, 0, 0);
      __builtin_amdgcn_s_setprio(0);
      if (idx + 4 < 64) LDB(bq[idx & 3], idx + 4)   // refill consumed buffer
    }
    // epilogue for this nt (pure registers; overlaps in-flight B loads)
    #pragma unroll
    for (int mf = 0; mf < 2; ++mf)
      #pragma unroll
      for (int reg = 0; reg < 4; ++reg) {
        float pp = 0.f;
        #pragma unroll
        for (int nf = 0; nf < 4; ++nf)
          pp += ftanh(acc[mf][nf][reg] + bl[nf]) * vl[nf];
        sp[mf][reg] += pp;
      }
  }
#undef LDB

  // reduce over the 16 n-lanes; combine the two nh waves via staging space
  float* sRed = (float*)sXw4;              // 64 floats needed; sXw dead
  float pv[2][4];
  #pragma unroll
  for (int mf = 0; mf < 2; ++mf)
    #pragma unroll
    for (int reg = 0; reg < 4; ++reg) {
      float p = sp[mf][reg];
      p += __shfl_xor(p, 1, 16);
      p += __shfl_xor(p, 2, 16);
      p += __shfl_xor(p, 4, 16);
      p += __shfl_xor(p, 8, 16);
      pv[mf][reg] = p;
    }
  __syncthreads();                         // re-sync drifted waves before sRed
  if (nh == 1 && lr == 0) {
    #pragma unroll
    for (int mf = 0; mf < 2; ++mf)
      #pragma unroll
      for (int reg = 0; reg < 4; ++reg)
        sRed[((mh * 2 + mf) * 4 + quad) * 4 + reg] = pv[mf][reg];
  }
  __syncthreads();
  if (nh == 0 && lr == 0) {
    #pragma unroll
    for (int mf = 0; mf < 2; ++mf)
      #pragma unroll
      for (int reg = 0; reg < 4; ++reg)
        s[mt * 64 + mh * 32 + mf * 16 + quad * 4 + reg] =
            pv[mf][reg] + sRed[((mh * 2 + mf) * 4 + quad) * 4 + reg];
  }
}

// ---------------------------------------------------------------------------
// win_weights: one thread per (b,p) window softmax -> wgt[b][p][16].
__global__ void win_weights(const float* __restrict__ s, const void* __restrict__ mask,
                            const int* __restrict__ flag, float* __restrict__ wgt) {
  int t = blockIdx.x * blockDim.x + threadIdx.x;
  if (t >= Bsz * LPOOL) return;
  int b = t / LPOOL, p = t - b * LPOOL;
  const bool u8 = (*flag != 0);
  const unsigned char* m8 = (const unsigned char*)mask;
  const int* m32 = (const int*)mask;
  float sv[16]; int mv[16];
  float mx = -3.4e38f;
  int base = b * Lsz + p * 8;
  #pragma unroll
  for (int w = 0; w < 16; ++w) {
    int mk = u8 ? (int)m8[base + w] : m32[base + w];
    float val = mk ? NEGV : s[base + w];
    sv[w] = val; mv[w] = mk;
    mx = fmaxf(mx, val);
  }
  float sum = 0.f;
  #pragma unroll
  for (int w = 0; w < 16; ++w) { sv[w] = expf(sv[w] - mx); sum += sv[w]; }
  float inv = 1.0f / sum;
  float norm = 0.f;
  #pragma unroll
  for (int w = 0; w < 16; ++w) { sv[w] = mv[w] ? 0.f : sv[w] * inv; norm += sv[w]; }
  norm = fmaxf(norm, 1e-6f);
  float rn = 1.0f / norm;
  #pragma unroll
  for (int w = 0; w < 16; ++w) wgt[t * 16 + w] = sv[w] * rn;
}

// ---------------------------------------------------------------------------
// pool_out: block = one (b,c) row. Coalesced 16 KB f32 row stage -> LDS;
// weights read is wave-contiguous (thread p reads 64 B at p*64); out write
// coalesced. Used by BOTH fast and fallback paths.
__global__ __launch_bounds__(256) void pool_out(const float* __restrict__ x,
    const float* __restrict__ wgt, float* __restrict__ out) {
  __shared__ float xrow[Lsz];
  int bc = blockIdx.x;
  int c = bc & (Csz - 1);
  int b = bc >> 9;
  const float* xr = x + ((size_t)b * Csz + c) * Lsz;
  int tid = threadIdx.x;
  #pragma unroll
  for (int it = 0; it < 4; ++it) {
    int idx = (tid + it * 256) << 2;
    *(float4*)(&xrow[idx]) = *(const float4*)(&xr[idx]);
  }
  __syncthreads();
  const float* wb = wgt + (size_t)b * LPOOL * 16;
  float* ob = out + ((size_t)b * Csz + c) * LPOOL;
  for (int p = tid; p < LPOOL; p += 256) {
    const float4* wp = (const float4*)(wb + p * 16);
    const float4* xp = (const float4*)(&xrow[p * 8]);
    float acc = 0.f;
    #pragma unroll
    for (int q = 0; q < 4; ++q) {
      float4 wv = wp[q], xv = xp[q];
      acc += xv.x * wv.x + xv.y * wv.y + xv.z * wv.z + xv.w * wv.w;
    }
    ob[p] = acc;
  }
}

// ---------------------------------------------------------------------------
// Fallback path kernels (only if ws too small for bf16 path)
__global__ void detect_mask(const unsigned char* __restrict__ mb, int* __restrict__ flag) {
  __shared__ int sf;
  int t = threadIdx.x;
  if (t == 0) sf = 0;
  __syncthreads();
  int f = 0;
  for (int i = t; i < 4096; i += 256)
    if ((i & 3) && mb[i]) f = 1;
  if (f) atomicOr(&sf, 1);
  __syncthreads();
  if (t == 0) *flag = sf;
}

__global__ __launch_bounds__(256) void gemm_s_f32(const float* __restrict__ x,
    const float* __restrict__ W, const float* __restrict__ bias,
    const float* __restrict__ v, float* __restrict__ s_out) {
  __shared__ float sA[32][64];
  __shared__ float sB[32][68];
  __shared__ float s_acc[64];
  const int tid = threadIdx.x;
  const int b = blockIdx.y;
  const int l0 = blockIdx.x * 64;
  if (tid < 64) s_acc[tid] = 0.0f;
  const int tx = tid & 15;
  const int ty = tid >> 4;
  const float* xb = x + ((size_t)b * Csz) * Lsz + l0;
  for (int d0 = 0; d0 < Csz; d0 += 64) {
    float acc[4][4] = {{0.f}};
    for (int c0 = 0; c0 < Csz; c0 += 32) {
      __syncthreads();
      #pragma unroll
      for (int it = 0; it < 8; ++it) {
        int idx = tid + it * 256;
        int kc = idx >> 6, ml = idx & 63;
        sA[kc][ml] = xb[(size_t)(c0 + kc) * Lsz + ml];
      }
      #pragma unroll
      for (int it = 0; it < 8; ++it) {
        int idx = tid + it * 256;
        int kc = idx & 31, dj = idx >> 5;
        sB[kc][dj] = W[(size_t)(d0 + dj) * Csz + c0 + kc];
      }
      __syncthreads();
      #pragma unroll
      for (int kc = 0; kc < 32; ++kc) {
        float4 a  = *(const float4*)(&sA[kc][tx << 2]);
        float4 w4 = *(const float4*)(&sB[kc][ty << 2]);
        acc[0][0] += a.x * w4.x; acc[0][1] += a.x * w4.y; acc[0][2] += a.x * w4.z; acc[0][3] += a.x * w4.w;
        acc[1][0] += a.y * w4.x; acc[1][1] += a.y * w4.y; acc[1][2] += a.y * w4.z; acc[1][3] += a.y * w4.w;
        acc[2][0] += a.z * w4.x; acc[2][1] += a.z * w4.y; acc[2][2] += a.z * w4.z; acc[2][3] += a.z * w4.w;
        acc[3][0] += a.w * w4.x; acc[3][1] += a.w * w4.y; acc[3][2] += a.w * w4.z; acc[3][3] += a.w * w4.w;
      }
    }
    float part[4] = {0.f, 0.f, 0.f, 0.f};
    #pragma unroll
    for (int j = 0; j < 4; ++j) {
      int d = d0 + (ty << 2) + j;
      float bj = bias[d], vj = v[d];
      #pragma unroll
      for (int i = 0; i < 4; ++i)
        part[i] += tanhf(acc[i][j] + bj) * vj;
    }
    #pragma unroll
    for (int i = 0; i < 4; ++i)
      atomicAdd(&s_acc[(tx << 2) + i], part[i]);
  }
  __syncthreads();
  if (tid < 64) s_out[(size_t)b * Lsz + l0 + tid] = s_acc[tid];
}

// ---------------------------------------------------------------------------
extern "C" void kernel_launch(void* const* d_in, const int* in_sizes, int n_in,
                              void* d_out, int out_size, void* d_ws, size_t ws_size,
                              hipStream_t stream) {
  const float* x    = (const float*)d_in[0];
  const void*  mask = d_in[1];
  const float* W    = (const float*)d_in[2];
  const float* bias = (const float*)d_in[3];
  const float* v    = (const float*)d_in[4];
  float* out = (float*)d_out;

  char* wsb = (char*)d_ws;
  int*   flag = (int*)wsb;                                   // 256 B
  float* s    = (float*)(wsb + 256);                         // 131072 B
  float* wgt  = (float*)(wsb + 131328);                      // 261632 B
  __hip_bfloat16* Wts = (__hip_bfloat16*)(wsb + 393216);     // 524288 B
  const size_t NEED = 917504;

  if (ws_size >= NEED) {
    prep<<<129, 256, 0, stream>>>((const unsigned char*)mask, flag, W, Wts);
    gemm_fused<<<512, 256, 0, stream>>>(x, Wts, bias, v, s);
    win_weights<<<(Bsz * LPOOL + 255) / 256, 256, 0, stream>>>(s, mask, flag, wgt);
    pool_out<<<Bsz * Csz, 256, 0, stream>>>(x, wgt, out);
  } else {
    detect_mask<<<1, 256, 0, stream>>>((const unsigned char*)mask, flag);
    gemm_s_f32<<<dim3(Lsz / 64, Bsz), 256, 0, stream>>>(x, W, bias, v, s);
    win_weights<<<(Bsz * LPOOL + 255) / 256, 256, 0, stream>>>(s, mask, flag, wgt);
    pool_out<<<Bsz * Csz, 256, 0, stream>>>(x, wgt, out);
  }
}